// Round 8
// baseline (434.036 us; speedup 1.0000x reference)
//
#include <hip/hip_runtime.h>
#include <hip/hip_bf16.h>

typedef __bf16 bf16_t;
typedef __attribute__((ext_vector_type(8))) __bf16 bf16x8;
typedef __attribute__((ext_vector_type(4))) __bf16 bf16x4;
typedef __attribute__((ext_vector_type(4))) float floatx4;
typedef __attribute__((ext_vector_type(4))) int intx4;
typedef __attribute__((ext_vector_type(4))) unsigned uintx4;

#define NN 8192
#define FIN 256
#define FOUT 64
#define GAT_ALPHA 0.2f
#define JSPLIT 4
#define JSEG (NN / JSPLIT)          // 2048 j per block
#define PHASEJ 256                  // j per phase (1 KB per row per DMA instr)
#define NPHASE (JSEG / PHASEJ)      // 8
#define NSTEPS (JSEG / 32)          // 64 K-steps total
#define ROWSTRIDE 268               // ints: 1072 B, 16B-aligned, 2-way banks only

// ---------------------------------------------------------------------------
// Kernel A: h = input @ W (fp32 in -> bf16 MFMA). Outputs:
//   hT [64][8192] bf16, E1/F1 fp32 [8192], ef2 packed (bf16 E2 | bf16 F2<<16).
// ---------------------------------------------------------------------------
__global__ __launch_bounds__(256) void gat_h_kernel(
    const float* __restrict__ input,    // [8192][256] fp32
    const float* __restrict__ W,        // [256][64] fp32
    const float* __restrict__ a,        // [128] fp32
    bf16_t* __restrict__ hT,            // [64][8192] bf16
    float* __restrict__ e1g, float* __restrict__ f1g,
    unsigned* __restrict__ ef2g)        // [8192] packed bf16 pair
{
    alignas(16) __shared__ bf16_t in_lds[32][264];
    alignas(16) __shared__ bf16_t wt_lds[64][264];
    __shared__ float h_lds[32][65];

    const int t  = threadIdx.x;
    const int i0 = blockIdx.x * 32;

    #pragma unroll
    for (int v = 0; v < 8; v++) {
        int u  = v * 256 + t;
        int i  = u >> 6;
        int k4 = (u & 63) * 4;
        floatx4 x = *(const floatx4*)(input + (size_t)(i0 + i) * FIN + k4);
        bf16x4 b;
        #pragma unroll
        for (int e = 0; e < 4; e++) b[e] = (bf16_t)x[e];
        *(bf16x4*)(&in_lds[i][k4]) = b;
    }
    #pragma unroll
    for (int v = 0; v < 16; v++) {
        int u  = v * 256 + t;
        int k  = u >> 4;
        int f4 = (u & 15) * 4;
        floatx4 wv = *(const floatx4*)(W + k * FOUT + f4);
        #pragma unroll
        for (int e = 0; e < 4; e++) wt_lds[f4 + e][k] = (bf16_t)wv[e];
    }
    __syncthreads();

    const int wave = t >> 6;
    const int lane = t & 63;
    const int i16  = (wave & 1) * 16;
    const int f32  = (wave >> 1) * 32;
    const int lm   = lane & 15;
    const int lq   = lane >> 4;

    floatx4 acc0 = {0.f, 0.f, 0.f, 0.f};
    floatx4 acc1 = {0.f, 0.f, 0.f, 0.f};
    #pragma unroll
    for (int ks = 0; ks < 8; ks++) {
        int ko = ks * 32 + lq * 8;
        bf16x8 af = *(const bf16x8*)(&in_lds[i16 + lm][ko]);
        bf16x8 b0 = *(const bf16x8*)(&wt_lds[f32 + lm][ko]);
        bf16x8 b1 = *(const bf16x8*)(&wt_lds[f32 + 16 + lm][ko]);
        acc0 = __builtin_amdgcn_mfma_f32_16x16x32_bf16(af, b0, acc0, 0, 0, 0);
        acc1 = __builtin_amdgcn_mfma_f32_16x16x32_bf16(af, b1, acc1, 0, 0, 0);
    }

    #pragma unroll
    for (int c = 0; c < 2; c++) {
        floatx4 acc = c ? acc1 : acc0;
        int f  = f32 + c * 16 + lm;
        int ib = i0 + i16 + lq * 4;
        bf16x4 hp;
        #pragma unroll
        for (int r = 0; r < 4; r++) hp[r] = (bf16_t)acc[r];
        *(bf16x4*)(hT + (size_t)f * NN + ib) = hp;
    }
    #pragma unroll
    for (int c = 0; c < 2; c++) {
        floatx4 acc = c ? acc1 : acc0;
        #pragma unroll
        for (int r = 0; r < 4; r++)
            h_lds[i16 + lq * 4 + r][f32 + c * 16 + lm] = acc[r];
    }
    __syncthreads();

    if (t < 64) {
        int r   = t & 31;
        int sel = t >> 5;
        const float* av = a + sel * FOUT;
        float s = 0.f;
        #pragma unroll 8
        for (int f = 0; f < FOUT; f++) s += h_lds[r][f] * av[f];
        int gi = i0 + r;
        float E = expf(s);
        float F = expf(GAT_ALPHA * s);
        if (sel == 0) {
            e1g[gi] = E; f1g[gi] = F;
        } else {
            unsigned eb = __builtin_bit_cast(unsigned short, (bf16_t)E);
            unsigned fb = __builtin_bit_cast(unsigned short, (bf16_t)F);
            ef2g[gi] = (fb << 16) | eb;
        }
    }
}

// ---------------------------------------------------------------------------
// Kernel B: producer/consumer wave-specialized fused softmax+aggregation.
// Block = 192 thr (3 waves), 32 rows x JSEG. Producer wave (2): adj-only
// global_load_lds DMA (1 KB/row/instr), vmcnt tracks ONLY adj -> clean
// one-phase-deep pipeline. Consumer waves (0,1): 16 rows each; ds_read adj
// + ef/hT L2 prefetch (their vmcnt tracks ONLY short-latency L2 loads) +
// w-compute + 5 MFMA (4 acc + ones-B rowsum). Raw s_barrier (no implicit
// waitcnt drain) -> consumer prefetches stay in flight across phases.
// ---------------------------------------------------------------------------
__global__ __launch_bounds__(192) void gat_att_kernel(
    const int* __restrict__ adj,        // [8192][8192] int32
    const bf16_t* __restrict__ hT,      // [64][8192] bf16
    const float* __restrict__ e1g, const float* __restrict__ f1g,
    const unsigned* __restrict__ ef2g,  // [8192] packed
    float* __restrict__ pacc,           // [JSPLIT][8192][64]
    float* __restrict__ prs)            // [JSPLIT][8192]
{
    __shared__ int abuf[2][32 * ROWSTRIDE];     // 68,608 B -> 2 blocks/CU

    const int t    = threadIdx.x;
    const int wave = t >> 6;
    const int lane = t & 63;
    const int bx   = blockIdx.x;
    const int js   = blockIdx.y;
    const int jb   = js * JSEG;
    const int bi0  = bx * 32;

    if (wave == 2) {
        // ------------------- PRODUCER -------------------
        // DMA(0)
        #pragma unroll
        for (int r = 0; r < 32; r++)
            __builtin_amdgcn_global_load_lds(
                (const __attribute__((address_space(1))) unsigned*)
                    (adj + (size_t)(bi0 + r) * NN + jb + lane * 4),
                (__attribute__((address_space(3))) unsigned*)
                    (&abuf[0][r * ROWSTRIDE]),
                16, 0, 0);
        for (int p = 0; p < NPHASE; p++) {
            asm volatile("s_waitcnt vmcnt(0)" ::: "memory");
            asm volatile("s_barrier" ::: "memory");    // phase p data ready
            if (p + 1 < NPHASE) {
                int* dst = abuf[(p + 1) & 1];
                #pragma unroll
                for (int r = 0; r < 32; r++)
                    __builtin_amdgcn_global_load_lds(
                        (const __attribute__((address_space(1))) unsigned*)
                            (adj + (size_t)(bi0 + r) * NN + jb
                             + (p + 1) * PHASEJ + lane * 4),
                        (__attribute__((address_space(3))) unsigned*)
                            (dst + r * ROWSTRIDE),
                        16, 0, 0);
            }
        }
        return;
    }

    // ------------------- CONSUMERS (waves 0,1) -------------------
    const int m   = lane & 15;          // row within 16 / C col f
    const int q   = lane >> 4;          // quad: k = q*8+e
    const int i0  = bi0 + wave * 16;    // this wave's first row
    const int lr  = wave * 16 + m;      // LDS row index

    const float E1 = e1g[i0 + m];
    const float F1 = f1g[i0 + m];

    const unsigned* efp = ef2g + jb + q * 8;
    const bf16_t*   htp = hT + (size_t)m * NN + jb + q * 8;

    floatx4 acc[4];
    #pragma unroll
    for (int c = 0; c < 4; c++) acc[c] = (floatx4){0.f, 0.f, 0.f, 0.f};
    floatx4 acc4 = {0.f, 0.f, 0.f, 0.f};   // rowsum via ones-B MFMA

    bf16x8 ones8;
    #pragma unroll
    for (int e = 0; e < 8; e++) ones8[e] = (bf16_t)1.0f;

    // K-step pipeline registers (prefetched 1 step ahead; L2-short latency)
    uintx4 e0 = *(const uintx4*)(efp);
    uintx4 e1 = *(const uintx4*)(efp + 4);
    bf16x8 hb[4];
    #pragma unroll
    for (int c = 0; c < 4; c++)
        hb[c] = *(const bf16x8*)(htp + (size_t)c * 16 * NN);

    for (int p = 0; p < NPHASE; p++) {
        asm volatile("s_barrier" ::: "memory");    // buf[p&1] ready
        const int* ap = abuf[p & 1] + lr * ROWSTRIDE + q * 8;

        #pragma unroll
        for (int ks = 0; ks < 8; ks++) {
            intx4 a0 = *(const intx4*)(ap + ks * 32);
            intx4 a1 = *(const intx4*)(ap + ks * 32 + 4);

            uintx4 ce0 = e0, ce1 = e1;
            bf16x8 ch0 = hb[0], ch1 = hb[1], ch2 = hb[2], ch3 = hb[3];
            const int s = p * 8 + ks;
            if (s + 1 < NSTEPS) {                  // runtime-false only at end
                e0 = *(const uintx4*)(efp + (s + 1) * 32);
                e1 = *(const uintx4*)(efp + (s + 1) * 32 + 4);
                #pragma unroll
                for (int c = 0; c < 4; c++)
                    hb[c] = *(const bf16x8*)(htp + (size_t)c * 16 * NN
                                             + (s + 1) * 32);
            }

            bf16x8 wf;
            #pragma unroll
            for (int e = 0; e < 8; e++) {
                int av     = (e < 4) ? a0[e] : a1[e - 4];
                unsigned v = (e < 4) ? ce0[e] : ce1[e - 4];
                float e2 = __builtin_bit_cast(float, v << 16);
                float f2 = __builtin_bit_cast(float, v & 0xffff0000u);
                float pv = fmaxf(E1 * e2, F1 * f2);
                wf[e] = (bf16_t)((av > 0) ? pv : 0.f);
            }
            acc[0] = __builtin_amdgcn_mfma_f32_16x16x32_bf16(wf, ch0, acc[0], 0, 0, 0);
            acc[1] = __builtin_amdgcn_mfma_f32_16x16x32_bf16(wf, ch1, acc[1], 0, 0, 0);
            acc[2] = __builtin_amdgcn_mfma_f32_16x16x32_bf16(wf, ch2, acc[2], 0, 0, 0);
            acc[3] = __builtin_amdgcn_mfma_f32_16x16x32_bf16(wf, ch3, acc[3], 0, 0, 0);
            acc4   = __builtin_amdgcn_mfma_f32_16x16x32_bf16(wf, ones8, acc4, 0, 0, 0);
        }
    }

    // rowsum: acc4[r] = rowsum(row q*4+r) in every column m; use m==0 lanes
    if (m == 0) {
        #pragma unroll
        for (int r = 0; r < 4; r++)
            prs[(size_t)js * NN + i0 + q * 4 + r] = acc4[r];
    }

    // partial acc: C layout col=m (f), row=q*4+r
    float* pa = pacc + (size_t)js * NN * FOUT;
    #pragma unroll
    for (int c = 0; c < 4; c++) {
        #pragma unroll
        for (int r = 0; r < 4; r++)
            pa[(size_t)(i0 + q * 4 + r) * FOUT + c * 16 + m] = acc[c][r];
    }
}

// ---------------------------------------------------------------------------
// Kernel C: combine JSPLIT partials, normalize, ELU, store fp32.
// ---------------------------------------------------------------------------
__global__ __launch_bounds__(256) void gat_combine_kernel(
    const float* __restrict__ pacc,     // [JSPLIT][8192][64]
    const float* __restrict__ prs,      // [JSPLIT][8192]
    float* __restrict__ out)            // [8192][64]
{
    int idx = blockIdx.x * 256 + threadIdx.x;
    int i   = idx >> 4;
    floatx4 s = {0.f, 0.f, 0.f, 0.f};
    float rs  = 0.f;
    #pragma unroll
    for (int js = 0; js < JSPLIT; js++) {
        s  += *(const floatx4*)(pacc + (size_t)js * NN * FOUT + (size_t)idx * 4);
        rs += prs[(size_t)js * NN + i];
    }
    float rinv = (rs > 0.f) ? 1.0f / rs : 0.f;
    floatx4 r;
    #pragma unroll
    for (int e = 0; e < 4; e++) {
        float x = s[e] * rinv;
        r[e] = (x > 0.f) ? x : (expf(x) - 1.0f);
    }
    *(floatx4*)(out + (size_t)idx * 4) = r;
}

// ---------------------------------------------------------------------------
extern "C" void kernel_launch(void* const* d_in, const int* in_sizes, int n_in,
                              void* d_out, int out_size, void* d_ws, size_t ws_size,
                              hipStream_t stream) {
    const float* input = (const float*)d_in[0];     // [8192][256] fp32
    const int*   adj   = (const int*)d_in[1];       // [8192][8192] int32
    const float* W     = (const float*)d_in[2];     // [256][64] fp32
    const float* a     = (const float*)d_in[3];     // [128] fp32
    float*       out   = (float*)d_out;             // [8192][64] fp32

    char* ws = (char*)d_ws;
    bf16_t*   hT   = (bf16_t*)ws;                   // 1 MiB
    float*    e1g  = (float*)(ws + (1 << 20));
    float*    f1g  = e1g + NN;
    unsigned* ef2g = (unsigned*)(f1g + NN);
    float*    pacc = (float*)(ef2g + NN);           // JSPLIT*8192*64*4 = 8 MiB
    float*    prs  = pacc + (size_t)JSPLIT * NN * FOUT;

    gat_h_kernel<<<NN / 32, 256, 0, stream>>>(input, W, a, hT, e1g, f1g, ef2g);

    dim3 gridB(NN / 32, JSPLIT);
    gat_att_kernel<<<gridB, 192, 0, stream>>>(adj, hT, e1g, f1g, ef2g,
                                              pacc, prs);

    gat_combine_kernel<<<NN * FOUT / 4 / 256, 256, 0, stream>>>(pacc, prs, out);
}